// Round 3
// baseline (258.917 us; speedup 1.0000x reference)
//
#include <hip/hip_runtime.h>

#define Bn 4
#define Cn 256
#define HWn 4096
#define CPn 64
#define MP 640   // CW rows padded 576 -> 640 (5 x 128)

typedef unsigned short u16;
typedef unsigned int u32;
typedef unsigned long long u64;

using short8  = __attribute__((ext_vector_type(8))) short;
using floatx4 = __attribute__((ext_vector_type(4))) float;

static __device__ __forceinline__ u16 f2bf(float f) {
    union { float f; u32 u; } v; v.f = f;
    u32 r = (v.u + 0x7FFFu + ((v.u >> 16) & 1u)) >> 16;
    return (u16)r;
}

// async global -> LDS, 16 B per lane. LDS dest = wave-uniform base + lane*16.
static __device__ __forceinline__ void gld16(const u16* g, u16* l) {
    __builtin_amdgcn_global_load_lds(
        (const __attribute__((address_space(1))) u32*)g,
        (__attribute__((address_space(3))) u32*)l, 16, 0, 0);
}

// ---------------------------------------------------------------------------
// Mega-kernel, software grid barrier (NO cooperative API).
// Grid 256 x 256 threads, 128 KB LDS -> exactly 1 block/CU, 256 CUs: all
// blocks resident => software barrier is safe. Counters zeroed by
// hipMemsetAsync before launch (graph-capture-safe).
// Phase bodies are verbatim R0-verified kernels, just re-sequenced.
// ---------------------------------------------------------------------------
__global__ __launch_bounds__(256, 1) void mega(
    const float* __restrict__ Tt, const float* __restrict__ Bt, const float* __restrict__ Mt,
    const float* __restrict__ Wqkv, const float* __restrict__ Wred, const float* __restrict__ Wrec,
    u16* __restrict__ xT, u16* __restrict__ CWp,
    float* __restrict__ Psum, float* __restrict__ Pmax,
    float* __restrict__ vout, u16* __restrict__ Mm,
    float* __restrict__ out, u32* __restrict__ gcnt)
{
    __shared__ __align__(16) u16 SM[65536];   // 128 KB, re-aliased per phase
    const int t   = threadIdx.x;
    const int blk = blockIdx.x;
    const int w = t >> 6, lane = t & 63;
    const int l15 = lane & 15, q = lane >> 4;
    const u32 nb = gridDim.x;

    // device-scope software barrier; distinct counter (own cacheline) per id
    auto gbar = [&](int id) {
        __syncthreads();
        if (t == 0) {
            __threadfence();                       // release prior writes
            atomicAdd(&gcnt[id * 16], 1u);
            int guard = 0;
            while (atomicAdd(&gcnt[id * 16], 0u) < nb && guard < 20000000) ++guard;
            __threadfence();                       // acquire others' writes
        }
        __syncthreads();
    };

    // ===================== Phase A: transpose + compose =====================
    {
        u16 (*T)[72] = (u16(*)[72])SM;
        const int cl = t >> 2, qq = t & 3;
        #pragma unroll 1
        for (int i = 0; i < 12; ++i) {
            const int tile = blk * 12 + i;               // 3072 tiles total
            const int hwt = tile & 63, ct = (tile >> 6) & 3;
            const int b = (tile >> 8) & 3, s = tile >> 10;
            const int c0 = ct * 64, hw0 = hwt * 64;
            const float* X = (s == 0 ? Tt : (s == 1 ? Bt : Mt)) + (size_t)b * Cn * HWn;
            const float* src = X + (size_t)(c0 + cl) * HWn + hw0 + qq * 16;
            #pragma unroll
            for (int u = 0; u < 4; ++u) {
                const float4 v = *(const float4*)(src + u * 4);
                u64 pk = (u64)f2bf(v.x) | ((u64)f2bf(v.y) << 16) |
                         ((u64)f2bf(v.z) << 32) | ((u64)f2bf(v.w) << 48);
                *(u64*)&T[cl][qq * 16 + u * 4] = pk;
            }
            __syncthreads();
            u16* dst = xT + ((size_t)((s * Bn + b) * HWn) + hw0 + cl) * Cn + c0 + qq * 16;
            #pragma unroll
            for (int u = 0; u < 2; ++u) {
                u32 w0 = (u32)T[qq*16+u*8+0][cl] | ((u32)T[qq*16+u*8+1][cl] << 16);
                u32 w1 = (u32)T[qq*16+u*8+2][cl] | ((u32)T[qq*16+u*8+3][cl] << 16);
                u32 w2 = (u32)T[qq*16+u*8+4][cl] | ((u32)T[qq*16+u*8+5][cl] << 16);
                u32 w3 = (u32)T[qq*16+u*8+6][cl] | ((u32)T[qq*16+u*8+7][cl] << 16);
                uint4 pk4 = {w0, w1, w2, w3};
                *(uint4*)(dst + u * 8) = pk4;
            }
            __syncthreads();
        }

        if (blk < 108) {       // CW compose: CWp[s](576x256) = Wred[idx] @ Wqkv
            float (*As)[64]  = (float(*)[64])SM;
            float (*Bsc)[64] = (float(*)[64])((char*)SM + 4096);
            const int c0   = (blk & 3) * 64;
            const int rest = blk >> 2;                   // 0..26
            const int y9 = rest % 9, s = rest / 9;
            const int tt = y9 / 3, m3 = y9 % 3;
            const int idx = (tt == 1) ? (3 * s + m3) : (3 * m3 + s);
            const float* A  = Wred + (size_t)idx * CPn * Cn;
            const float* Bm = Wqkv + (size_t)(3 * s + tt) * Cn * Cn;
            const int ty = t >> 4, tx = t & 15;
            float acc[4][4] = {};
            for (int k0 = 0; k0 < Cn; k0 += 16) {
                {
                    const int r = t >> 2, eq = (t & 3) * 4;
                    const float4 a = *(const float4*)(A + (size_t)r * Cn + k0 + eq);
                    As[eq+0][r]=a.x; As[eq+1][r]=a.y; As[eq+2][r]=a.z; As[eq+3][r]=a.w;
                }
                {
                    const int r = t >> 4, cq = (t & 15) * 4;
                    *(float4*)(&Bsc[r][cq]) = *(const float4*)(Bm + (size_t)(k0+r)*Cn + c0 + cq);
                }
                __syncthreads();
                #pragma unroll
                for (int k = 0; k < 16; ++k) {
                    const float4 a4 = *(const float4*)(&As[k][ty*4]);
                    const float4 b4 = *(const float4*)(&Bsc[k][tx*4]);
                    const float a_[4]  = {a4.x, a4.y, a4.z, a4.w};
                    const float bb_[4] = {b4.x, b4.y, b4.z, b4.w};
                    #pragma unroll
                    for (int i2 = 0; i2 < 4; ++i2)
                        #pragma unroll
                        for (int j2 = 0; j2 < 4; ++j2)
                            acc[i2][j2] = fmaf(a_[i2], bb_[j2], acc[i2][j2]);
                }
                __syncthreads();
            }
            u16* outp = CWp + (size_t)s * MP * Cn;
            #pragma unroll
            for (int i2 = 0; i2 < 4; ++i2) {
                const int row = tt * 192 + m3 * 64 + ty * 4 + i2;
                u64 pk = (u64)f2bf(acc[i2][0]) | ((u64)f2bf(acc[i2][1]) << 16) |
                         ((u64)f2bf(acc[i2][2]) << 32) | ((u64)f2bf(acc[i2][3]) << 48);
                *(u64*)(outp + (size_t)row * Cn + c0 + tx * 4) = pk;
            }
        }
    }
    gbar(0);

    // ===================== Phase B: redpool GEMM (R0 body) ===================
    // 240 units = 5 mt x 16 nch x 3 s.  A-tile 128x256 in VGPRs; 16 n-subtiles
    // of 64 cols, B dbuf 2x32 KB in LDS; relu+pool in registers.
    if (blk < 240) {
        const int s = blk / 80, r80 = blk % 80;
        const int mt = r80 >> 4, nch = r80 & 15;
        const int m0 = mt * 128;
        const int nbase = nch * 1024;
        const u16* Ap = CWp + (size_t)s * MP * Cn;
        const u16* Bp = xT + (size_t)s * Bn * HWn * Cn;
        const int wr = w >> 1, wc = w & 1;

        short8 af[4][8];
        {
            const u16* Arow = Ap + (size_t)(m0 + wr * 64 + l15) * Cn + q * 8;
            #pragma unroll
            for (int i = 0; i < 4; ++i)
                #pragma unroll
                for (int kk = 0; kk < 8; ++kk)
                    af[i][kk] = *(const short8*)(Arow + (size_t)(i * 16) * Cn + kk * 32);
        }

        u16* const LB0 = SM;            // 32 KB
        u16* const LB1 = SM + 16384;    // 32 KB
        auto stageB = [&](int it, u16* dstb) {
            const u16* Bsrc = Bp + (size_t)(nbase + it * 64 + l15) * Cn + q * 8;
            #pragma unroll
            for (int pi = 0; pi < 8; ++pi) {
                const int p = w * 8 + pi;
                gld16(Bsrc + (size_t)((p >> 3) * 16) * Cn + (p & 7) * 32, dstb + p * 512);
            }
        };
        stageB(0, LB0);

        float rs[4][4] = {};
        float rm[4][4] = {};

        for (int it = 0; it < 16; ++it) {
            __syncthreads();                        // drains B[it]; prev compute done
            if (it + 1 < 16) stageB(it + 1, ((it + 1) & 1) ? LB1 : LB0);
            const u16* bb = (it & 1) ? LB1 : LB0;

            floatx4 acc[4][2] = {};
            __builtin_amdgcn_s_setprio(1);
            #pragma unroll
            for (int kk = 0; kk < 8; ++kk) {
                short8 bf[2];
                #pragma unroll
                for (int j = 0; j < 2; ++j)
                    bf[j] = *(const short8*)&bb[((wc * 2 + j) * 8 + kk) * 512 + lane * 8];
                #pragma unroll
                for (int i = 0; i < 4; ++i)
                    #pragma unroll
                    for (int j = 0; j < 2; ++j)
                        acc[i][j] = __builtin_amdgcn_mfma_f32_16x16x32_bf16(af[i][kk], bf[j], acc[i][j], 0, 0, 0);
            }
            __builtin_amdgcn_s_setprio(0);
            #pragma unroll
            for (int i = 0; i < 4; ++i)
                #pragma unroll
                for (int r = 0; r < 4; ++r) {
                    const float v0 = fmaxf(acc[i][0][r], 0.f);
                    const float v1 = fmaxf(acc[i][1][r], 0.f);
                    rs[i][r] += v0 + v1;
                    rm[i][r] = fmaxf(rm[i][r], fmaxf(v0, v1));
                }
        }

        // reduce over the 16 cols within the wave's half-tile
        #pragma unroll
        for (int i = 0; i < 4; ++i)
            #pragma unroll
            for (int r = 0; r < 4; ++r) {
                #pragma unroll
                for (int off = 1; off < 16; off <<= 1) {
                    rs[i][r] += __shfl_xor(rs[i][r], off);
                    rm[i][r] = fmaxf(rm[i][r], __shfl_xor(rm[i][r], off));
                }
            }

        __syncthreads();
        float* Lsum = (float*)SM;              // [2][128]
        float* Lmax = Lsum + 256;
        if (l15 == 0) {
            #pragma unroll
            for (int i = 0; i < 4; ++i)
                #pragma unroll
                for (int r = 0; r < 4; ++r) {
                    const int row = wr * 64 + i * 16 + q * 4 + r;
                    Lsum[wc * 128 + row] = rs[i][r];
                    Lmax[wc * 128 + row] = rm[i][r];
                }
        }
        __syncthreads();
        if (t < 128) {
            const int R = m0 + t;
            const size_t o = ((size_t)s * MP + R) * 16 + nch;
            Psum[o] = Lsum[t] + Lsum[128 + t];
            Pmax[o] = fmaxf(Lmax[t], Lmax[128 + t]);
        }
    }
    gbar(1);

    // ===================== Phase C: tiny attention (36 units) ================
    if (blk < 36) {
        float* ff = (float*)SM;
        float* gg = ff + 64;
        float* hh = ff + 128;
        const int idx = blk >> 2, bb2 = blk & 3;
        if (t < 64) {
            float v[3];
            #pragma unroll
            for (int tt = 0; tt < 3; ++tt) {
                const int s_ = (tt == 1) ? idx / 3 : idx % 3;
                const int m3 = (tt == 1) ? idx % 3 : idx / 3;
                const int R  = tt * 192 + m3 * 64 + t;
                const size_t base = ((size_t)s_ * MP + R) * 16 + bb2 * 4;
                float sm = 0.f, mx = 0.f;
                #pragma unroll
                for (int u = 0; u < 4; ++u) {
                    sm += Psum[base + u];
                    mx = fmaxf(mx, Pmax[base + u]);
                }
                v[tt] = sm * (1.0f / HWn) + mx;
            }
            gg[t] = v[0];   // Q-pool
            ff[t] = v[1];   // K-pool
            hh[t] = v[2];   // V-pool
        }
        __syncthreads();
        if (t < 64) {
            const float gj = gg[t];
            float mx = -1e30f;
            for (int i = 0; i < CPn; ++i) mx = fmaxf(mx, ff[i] * gj);
            float den = 0.f, num = 0.f;
            for (int i = 0; i < CPn; ++i) {
                const float e = expf(ff[i] * gj - mx);
                den += e;
                num += hh[i] * e;
            }
            vout[((size_t)idx * Bn + bb2) * CPn + t] = num / den;
        }
    }
    gbar(2);

    // ===================== Phase D: build Mm (12 units/block) ================
    {
        float* cc = (float*)SM;
        #pragma unroll 1
        for (int i = 0; i < 12; ++i) {
            const int unit = blk * 12 + i;          // 3072 = (s*256+m)*4+b
            const int b = unit & 3, m = (unit >> 2) & 255, s = unit >> 10;
            if (t < CPn) {
                float d[6];
                #pragma unroll
                for (int j = 0; j < 6; ++j) {
                    const int idx = (j < 3) ? (s + 3 * j) : (3 * s + (j - 3));
                    d[j] = vout[((size_t)idx * Bn + b) * CPn + t] *
                           Wrec[((size_t)idx * Cn + m) * CPn + t];
                }
                #pragma unroll
                for (int off = 32; off >= 1; off >>= 1)
                    #pragma unroll
                    for (int j = 0; j < 6; ++j)
                        d[j] += __shfl_xor(d[j], off);
                if (t == 0) {
                    float cA = 0.f, cK = 0.f;
                    #pragma unroll
                    for (int j = 0; j < 3; ++j) {
                        cA += 1.0f / (1.0f + expf(-d[j]));
                        cK += 1.0f / (1.0f + expf(-d[j + 3]));
                    }
                    cc[0] = cA; cc[1] = cK;
                }
            }
            __syncthreads();
            const float cA = cc[0], cK = cc[1];
            const float wq = Wqkv[((size_t)(3 * s + 0) * Cn + m) * Cn + t];
            const float wk = Wqkv[((size_t)(3 * s + 1) * Cn + m) * Cn + t];
            const float wv = Wqkv[((size_t)(3 * s + 2) * Cn + m) * Cn + t];
            Mm[((size_t)(b * 256 + m)) * 768 + s * 256 + t] = f2bf(cA * (wq + wv) + cK * wk);
            __syncthreads();
        }
    }
    gbar(3);

    // ===================== Phase E: final GEMM (256 units, R0 body) ==========
    {
        const int b  = blk >> 6, rest = blk & 63;
        const int mt = rest >> 5, nt = rest & 31;
        const int m0 = mt * 128, n0 = nt * 128;
        u16* const A0 = SM;            // 2 bufs x 32 KB
        u16* const B0 = SM + 32768;    // 2 bufs x 32 KB
        const int rb = (w >> 1) * 64, cb = (w & 1) * 64;

        auto stage = [&](int it, int bufofs) {
            const int k0 = it * 128;
            const int s = k0 >> 8, c0 = k0 & 255;
            const u16* Asrc = Mm + (size_t)(b * 256 + m0 + l15) * 768 + k0 + q * 8;
            const u16* Bsrc = xT + ((size_t)((s * Bn + b) * HWn) + n0 + l15) * Cn + c0 + q * 8;
            #pragma unroll
            for (int pi = 0; pi < 8; ++pi) {
                const int p = w * 8 + pi;
                const size_t roff = (size_t)((p >> 2) * 16);
                gld16(Asrc + roff * 768 + (p & 3) * 32, A0 + bufofs + p * 512);
                gld16(Bsrc + roff * Cn + (p & 3) * 32, B0 + bufofs + p * 512);
            }
        };
        stage(0, 0);

        floatx4 acc[4][4] = {};

        for (int it = 0; it < 6; ++it) {
            __syncthreads();
            if (it + 1 < 6) stage(it + 1, ((it + 1) & 1) * 16384);
            const u16* as = A0 + (it & 1) * 16384;
            const u16* bs = B0 + (it & 1) * 16384;
            #pragma unroll
            for (int kk = 0; kk < 4; ++kk) {
                short8 af2[4], bf2[4];
                #pragma unroll
                for (int i = 0; i < 4; ++i)
                    af2[i] = *(const short8*)&as[((((w >> 1) * 4 + i) << 2) + kk) * 512 + lane * 8];
                #pragma unroll
                for (int j = 0; j < 4; ++j)
                    bf2[j] = *(const short8*)&bs[((((w & 1) * 4 + j) << 2) + kk) * 512 + lane * 8];
                #pragma unroll
                for (int i = 0; i < 4; ++i)
                    #pragma unroll
                    for (int j = 0; j < 4; ++j)
                        acc[i][j] = __builtin_amdgcn_mfma_f32_16x16x32_bf16(af2[i], bf2[j], acc[i][j], 0, 0, 0);
            }
        }

        #pragma unroll
        for (int i = 0; i < 4; ++i)
            #pragma unroll
            for (int j = 0; j < 4; ++j)
                #pragma unroll
                for (int r = 0; r < 4; ++r) {
                    const int row = m0 + rb + i * 16 + q * 4 + r;
                    const int col = n0 + cb + j * 16 + l15;
                    out[((size_t)(b * 256) + row) * HWn + col] = acc[i][j][r];
                }
    }
}

extern "C" void kernel_launch(void* const* d_in, const int* in_sizes, int n_in,
                              void* d_out, int out_size, void* d_ws, size_t ws_size,
                              hipStream_t stream)
{
    const float* Tt   = (const float*)d_in[0];
    const float* Bt   = (const float*)d_in[1];
    const float* Mt   = (const float*)d_in[2];
    const float* Wqkv = (const float*)d_in[3];
    const float* Wred = (const float*)d_in[4];
    const float* Wrec = (const float*)d_in[5];
    float* out = (float*)d_out;

    unsigned char* p = (unsigned char*)d_ws;
    u16* xT = (u16*)p;            p += (size_t)3 * Bn * HWn * Cn * 2;   // 25.2 MB
    u16* Mm = (u16*)p;            p += (size_t)Bn * 256 * 768 * 2;      // 1.57 MB
    u16* CWp = (u16*)p;           p += (size_t)3 * MP * Cn * 2;         // 983 KB
    float* Psum = (float*)p;      p += (size_t)3 * MP * 16 * 4;         // 123 KB
    float* Pmax = (float*)p;      p += (size_t)3 * MP * 16 * 4;         // 123 KB
    float* vout = (float*)p;      p += (size_t)9 * Bn * CPn * 4;        // 9.2 KB
    u32* gcnt = (u32*)p;          p += 256;                             // barrier counters

    hipMemsetAsync(gcnt, 0, 256, stream);
    mega<<<dim3(256), dim3(256), 0, stream>>>(Tt, Bt, Mt, Wqkv, Wred, Wrec,
                                              xT, CWp, Psum, Pmax, vout, Mm, out, gcnt);
}